// Round 10
// baseline (251.410 us; speedup 1.0000x reference)
//
#include <hip/hip_runtime.h>
#include <math.h>

#define N_TS 4096
#define SEQ  168
#define HOR  24
#define T_ALL 192
#define F_INP 32
#define HID  64
#define NROW 192            // compacted gate rows: i(64) g(64) o(64)
#define NB_B (N_TS / 16)    // 256 autoregressive blocks (16 series each)
#define NT_B ((N_TS * SEQ) / 256)  // 2688 teacher blocks (4 tiles x 64 instances)
#define L2E  1.44269504089f
#define W16F_L1  6144       // half-offset of standard layer-1 weights (AR path)
#define W16F_L1P 18432      // half-offset of PHASE-MAJOR permuted layer-1 weights

typedef _Float16 half8  __attribute__((ext_vector_type(8)));
typedef _Float16 half4  __attribute__((ext_vector_type(4)));
typedef float    floatx4 __attribute__((ext_vector_type(4)));

__device__ __forceinline__ float fexp(float x)  { return __expf(x); }
__device__ __forceinline__ float ex2(float x)   { return __builtin_amdgcn_exp2f(x); }
__device__ __forceinline__ float frcp(float x)  { return __builtin_amdgcn_rcpf(x); }
__device__ __forceinline__ float softplus_(float x) { return (x > 15.0f) ? x : __logf(1.0f + fexp(x)); }

// Gates arrive PRESCALED: i,o rows x(-log2e); g rows x(-2*log2e) — folded into
// weights/biases, so every sigmoid/tanh exp is a bare v_exp (2^x).
__device__ __forceinline__ float lstm_h(float ip, float gp, float op) {
    const float Ei = ex2(ip);
    const float Eg = ex2(gp);
    const float cc = (1.0f - Eg) * frcp((1.0f + Ei) * (1.0f + Eg));
    const float Ec = ex2(cc * (-2.0f * L2E));
    const float Eo = ex2(op);
    return (1.0f - Ec) * frcp((1.0f + Ec) * (1.0f + Eo));
}

__device__ __forceinline__ half8 cvt8(const float4 a, const float4 b) {
    half8 v;
    v[0]=(_Float16)a.x; v[1]=(_Float16)a.y; v[2]=(_Float16)a.z; v[3]=(_Float16)a.w;
    v[4]=(_Float16)b.x; v[5]=(_Float16)b.y; v[6]=(_Float16)b.z; v[7]=(_Float16)b.w;
    return v;
}

// ---------------------------------------------------------------------------
// prep: compacted (f dropped), PRESCALED weights in k-chunked fragment layout
//   layer 0 (x-cols only, k<32): W16f[(kb*192+row)*8+kp], kb in [0,4)
//   layer 1 standard (AR path):  W16f[W16F_L1 + (kb*192+row)*8+kp], k = hid
//   layer 1 permuted PHASE-MAJOR (teacher): W16F_L1P +
//       h*6144 + ((kb*96 + gate*32 + jtl*16 + r16)*8 + kp), jt = h*2+jtl,
//     column k = pi(hid):  k=q*8+2*d+e     <-> hid=d*16+q*4+e      (k < 32)
//                          k=32+q*8+2*d+e  <-> hid=d*16+q*4+2+e    (k >= 32)
//   so the teacher's own L0 output registers ARE its L1 B-fragment (no exchange),
//   and each 12 KB phase-half is self-contained (all gates, both k-halves).
// Rank-1 embed fold (prescaled): wy1 = W1[:,32:]@W_embed ; b1c = b1 + W1[:,32:]@b_embed.
// ---------------------------------------------------------------------------
__global__ __launch_bounds__(256) void prep(
    const float* __restrict__ W_ih, const float* __restrict__ b_ih,
    const float* __restrict__ b_hh,
    const float* __restrict__ W_embed, const float* __restrict__ b_embed,
    _Float16* __restrict__ W16f, float* __restrict__ bsum,
    float* __restrict__ wy1, float* __restrict__ b1c)
{
    const int idx = blockIdx.x * 256 + threadIdx.x;
    // layer 0: x-cols only
    for (int i = idx; i < 4 * NROW * 8; i += gridDim.x * 256) {
        const int kp  = i & 7;
        const int row = (i >> 3) % NROW;
        const int kb  = (i >> 3) / NROW;                   // 0..3 -> k = kb*8+kp < 32
        const int sr  = (row < 64) ? row : row + 64;       // skip dead f rows
        const float sc = (row >= 64 && row < 128) ? (-2.0f * L2E) : (-L2E);
        W16f[i] = (_Float16)(W_ih[sr * HID + kb * 8 + kp] * sc);
    }
    // layer 1 standard (k = hid identity) — AR path
    for (int i = idx; i < 8 * NROW * 8; i += gridDim.x * 256) {
        const int kp  = i & 7;
        const int row = (i >> 3) % NROW;
        const int kb  = (i >> 3) / NROW;                   // 0..7
        const int sr  = (row < 64) ? row : row + 64;
        const float sc = (row >= 64 && row < 128) ? (-2.0f * L2E) : (-L2E);
        W16f[W16F_L1 + i] = (_Float16)(W_ih[(256 + sr) * HID + kb * 8 + kp] * sc);
    }
    // layer 1 permuted, phase-major (teacher)
    for (int i = idx; i < 2 * 6144; i += gridDim.x * 256) {
        const int h    = i / 6144;
        const int rem  = i - h * 6144;
        const int kp   = rem & 7;
        const int t    = rem >> 3;                         // 0..767
        const int rowb = t % 96;
        const int kb   = t / 96;                           // 0..7
        const int gate = rowb >> 5;                        // 0:i 1:g 2:o
        const int jtl  = (rowb >> 4) & 1;
        const int r16  = rowb & 15;
        const int jt   = h * 2 + jtl;
        const int srow = gate * 64 + jt * 16 + r16;        // compacted row 0..191
        const int sr   = (srow < 64) ? srow : srow + 64;   // skip dead f rows
        const int k    = kb * 8 + kp;                      // logical k = pi(hid)
        const int kk   = k & 31;
        const int d    = (kk >> 1) & 3;
        const int q    = kk >> 3;
        const int e    = kk & 1;
        const int hid  = d * 16 + q * 4 + ((k >> 5) << 1) + e;
        const float sc = (gate == 1) ? (-2.0f * L2E) : (-L2E);
        W16f[W16F_L1P + i] = (_Float16)(W_ih[(256 + sr) * HID + hid] * sc);
    }
    for (int i = idx; i < 2 * NROW; i += gridDim.x * 256) {
        const int r = i % NROW;
        const int l = i / NROW;
        const int sr = (r < 64) ? r : r + 64;
        const float sc = (r >= 64 && r < 128) ? (-2.0f * L2E) : (-L2E);
        bsum[i] = (b_ih[l * 256 + sr] + b_hh[l * 256 + sr]) * sc;
    }
    if (idx < NROW) {
        const int sr = (idx < 64) ? idx : idx + 64;
        const float sc = (idx >= 64 && idx < 128) ? (-2.0f * L2E) : (-L2E);
        const float* wrow = W_ih + sr * HID + 32;          // layer 0, cols 32..63
        float s1 = 0.f, s2 = 0.f;
        #pragma unroll
        for (int k = 0; k < 32; ++k) {
            s1 = fmaf(wrow[k], W_embed[k], s1);
            s2 = fmaf(wrow[k], b_embed[k], s2);
        }
        wy1[idx] = s1 * sc;
        b1c[idx] = (b_ih[sr] + b_hh[sr] + s2) * sc;
    }
}

// ---------------------------------------------------------------------------
// fused, 256-thread blocks (4 waves):
//  blocks [0, NB_B): autoregressive path — proven 16-series form, persistent
//   register fragments, XOR-swizzled slab, 2 barriers/step. Unchanged (r9).
//  blocks [NB_B, ...): teacher path, 4 tiles x 64 instances per block:
//   stage L1P (24K) + bias vectors (2.3K) once, ONE barrier, then 4
//   barrier-free staging-free tiles. L0 weights (12 KB, L1-cache-resident,
//   shared by all blocks) + W_mu/W_sigma read GLOBAL-DIRECT — r4's failure
//   was a 36 KB global footprint; 12.5 KB fits L1. Memory clobber per tile
//   defeats LICM hoisting (r8 lesson: VGPR 188).
//  LDS union = 26880 B -> 6 blocks/CU (24 waves/CU, 75% ceiling), VGPR ~56.
// ---------------------------------------------------------------------------
__global__ __launch_bounds__(256, 6) void fused(
    const float* __restrict__ X,
    const float* __restrict__ y,
    const float* __restrict__ Xf,
    const float* __restrict__ W_embed,
    const float* __restrict__ b_embed,
    const _Float16* __restrict__ W16f,
    const float* __restrict__ bsum,
    const float* __restrict__ wy1,
    const float* __restrict__ b1c,
    const float* __restrict__ W_mu,
    const float* __restrict__ b_mu,
    const float* __restrict__ W_sigma,
    const float* __restrict__ b_sigma,
    float* __restrict__ out)
{
    __shared__ union __align__(16) {
        struct {                                           // teacher: 26880 B
            _Float16 Wlh[2][6144];                         // L1P halves, 24 KB
            float b1cb[NROW]; float wy1b[NROW]; float bs1b[NROW];
        } A;
        struct { _Float16 slab[16 * 64]; float partm[16][4]; float parts[16][4];
                 float wyb[NROW]; float b1cb[NROW]; } B;                 // ~4.1 KB
    } sh;

    const int tid = threadIdx.x;
    float* mu_out = out + (size_t)N_TS * HOR;
    float* sg_out = mu_out + (size_t)N_TS * T_ALL;

    if (blockIdx.x < NB_B) {
        // =================== autoregressive path (4 waves) ===================
        __builtin_amdgcn_s_setprio(1);           // beat co-resident teacher waves
        const int w    = tid >> 6;
        const int lane = tid & 63;
        const int quad = lane >> 4;
        const int ln   = lane & 15;
        const int n0   = blockIdx.x * 16;

        if (tid < NROW) {
            sh.B.wyb[tid]  = wy1[tid];
            sh.B.b1cb[tid] = b1c[tid];
        }

        // persistent register fragments (wave w owns row-tiles rt = j*4+w)
        half8 B1[3];        // W1 rows, k<32 (embed cols via rank-1 fold)
        half8 B2[3][2];     // W2 rows, full k (STANDARD layout)
        float bias2[3];
        #pragma unroll
        for (int j = 0; j < 3; ++j) {
            const int rt = j * 4 + w;
            B1[j] = *(const half8*)(W16f + ((size_t)quad * NROW + rt * 16 + ln) * 8);
            #pragma unroll
            for (int kt = 0; kt < 2; ++kt)
                B2[j][kt] = *(const half8*)(W16f + W16F_L1 + ((size_t)(kt * 4 + quad) * NROW + rt * 16 + ln) * 8);
            bias2[j] = bsum[NROW + rt * 16 + ln];
        }
        const float wmu = W_mu[w * 16 + ln], wsg = W_sigma[w * 16 + ln];
        const float bmu = b_mu[0], bsg = b_sigma[0];

        // bootstrap inputs: t = 167
        const float* xfp = Xf + (size_t)(n0 + ln) * HOR * F_INP + quad * 8;
        float4 xa, xb;
        {
            const float* xp = X + ((size_t)(n0 + ln) * SEQ + (SEQ - 1)) * F_INP + quad * 8;
            xa = *(const float4*)xp;
            xb = *(const float4*)(xp + 4);
        }
        float ycur = y[(size_t)(n0 + ln) * SEQ + (SEQ - 1)];
        __syncthreads();                         // wyb/b1cb visible

        #pragma unroll 1
        for (int it = 0; it <= HOR + 1; ++it) {
            if (it > 0) {
                // finalize step k = it-1 (redundant per-lane, bit-identical)
                const int k = it - 1;
                const float4 m4 = *(const float4*)sh.B.partm[ln];
                const float4 s4 = *(const float4*)sh.B.parts[ln];
                const float mu = (m4.x + m4.y) + (m4.z + m4.w) + bmu;
                const float sg = softplus_((s4.x + s4.y) + (s4.z + s4.w) + bsg) + 1e-6f;
                const float d  = ycur - mu;
                const float is = frcp(sg);
                const float lik = 0.39894228040143267f * is * fexp(-0.5f * d * d * is * is);
                if (k > 0 && w == 0 && quad == 0) {
                    const int nn = n0 + ln;
                    const int t  = SEQ + k - 1;
                    mu_out[(size_t)nn * T_ALL + t] = mu;
                    sg_out[(size_t)nn * T_ALL + t] = sg;
                    if (k < HOR) out[(size_t)nn * HOR + k] = lik;
                }
                ycur = lik;
            }
            if (it > HOR) break;

            // ---- compute step it (input carry = ycur) ----
            const half8 xf0 = cvt8(xa, xb);
            if (it < HOR) {                      // next iter uses Xf step it
                xa = *(const float4*)(xfp + it * F_INP);
                xb = *(const float4*)(xfp + it * F_INP + 4);
            }

            // layer 1: 3 MFMAs; C row = unit-in-tile (quad*4+r), col = series(ln)
            floatx4 t0 = *(const floatx4*)(sh.B.b1cb + 0 * 64 + w * 16 + quad * 4);
            floatx4 t1 = *(const floatx4*)(sh.B.b1cb + 1 * 64 + w * 16 + quad * 4);
            floatx4 t2 = *(const floatx4*)(sh.B.b1cb + 2 * 64 + w * 16 + quad * 4);
            t0 = __builtin_amdgcn_mfma_f32_16x16x32_f16(B1[0], xf0, t0, 0, 0, 0);
            t1 = __builtin_amdgcn_mfma_f32_16x16x32_f16(B1[1], xf0, t1, 0, 0, 0);
            t2 = __builtin_amdgcn_mfma_f32_16x16x32_f16(B1[2], xf0, t2, 0, 0, 0);

            const floatx4 wy0  = *(const floatx4*)(sh.B.wyb + 0 * 64 + w * 16 + quad * 4);
            const floatx4 wy1v = *(const floatx4*)(sh.B.wyb + 1 * 64 + w * 16 + quad * 4);
            const floatx4 wy2  = *(const floatx4*)(sh.B.wyb + 2 * 64 + w * 16 + quad * 4);

            half4 h1p;
            #pragma unroll
            for (int r = 0; r < 4; ++r) {
                const float ig = fmaf(ycur, wy0[r],  t0[r]);
                const float gg = fmaf(ycur, wy1v[r], t1[r]);
                const float og = fmaf(ycur, wy2[r],  t2[r]);
                h1p[r] = (_Float16)lstm_h(ig, gg, og);
            }
            // XOR-swizzled slab write: unit 16B-block = 2*w + (quad>>1)
            {
                const int xblk = (2 * w + (quad >> 1)) ^ (ln & 7);
                *(half4*)(&sh.B.slab[ln * 64 + xblk * 8 + (quad & 1) * 4]) = h1p;
            }
            __syncthreads();

            // layer 2: A = h1 series-frag (swizzled reads)
            const half8 a0 = *(const half8*)(&sh.B.slab[ln * 64 + ((quad ^ (ln & 7)) << 3)]);
            const half8 a1 = *(const half8*)(&sh.B.slab[ln * 64 + (((4 + quad) ^ (ln & 7)) << 3)]);
            floatx4 acc[3];
            #pragma unroll
            for (int j = 0; j < 3; ++j) {
                acc[j] = (floatx4){bias2[j], bias2[j], bias2[j], bias2[j]};
                acc[j] = __builtin_amdgcn_mfma_f32_16x16x32_f16(a0, B2[j][0], acc[j], 0, 0, 0);
                acc[j] = __builtin_amdgcn_mfma_f32_16x16x32_f16(a1, B2[j][1], acc[j], 0, 0, 0);
            }

            // act L2 + head partials: unit w*16+ln, series quad*4+r
            float pmr[4], psr[4];
            #pragma unroll
            for (int r = 0; r < 4; ++r) {
                const float hh = lstm_h(acc[0][r], acc[1][r], acc[2][r]);
                const float hr = fmaxf(hh, 0.0f);
                pmr[r] = hr * wmu;
                psr[r] = hr * wsg;
            }
            #pragma unroll
            for (int off = 1; off < 16; off <<= 1) {
                #pragma unroll
                for (int r = 0; r < 4; ++r) {
                    pmr[r] += __shfl_xor(pmr[r], off, 64);
                    psr[r] += __shfl_xor(psr[r], off, 64);
                }
            }
            if (ln == 0) {
                #pragma unroll
                for (int r = 0; r < 4; ++r) {
                    sh.B.partm[quad * 4 + r][w] = pmr[r];
                    sh.B.parts[quad * 4 + r][w] = psr[r];
                }
            }
            __syncthreads();
        }
        return;
    }

    // ======================= teacher-forced path (4 waves) =======================
    const int w    = tid >> 6;
    const int lane = tid & 63;
    const int quad = lane >> 4;
    const int ln   = lane & 15;

    // ---- one-time stage: both L1P halves (24K) + bias vectors (2.3K) ----
    #pragma unroll
    for (int c = 0; c < 3; ++c) {
        const int off = (c * 256 + tid) * 8;
        *(half8*)(sh.A.Wlh[0] + off) = *(const half8*)(W16f + W16F_L1P + off);
        *(half8*)(sh.A.Wlh[1] + off) = *(const half8*)(W16f + W16F_L1P + 6144 + off);
    }
    if (tid < NROW) {
        sh.A.b1cb[tid] = b1c[tid];
        sh.A.wy1b[tid] = wy1[tid];
        sh.A.bs1b[tid] = bsum[NROW + tid];
    }
    __syncthreads();                 // the ONLY barrier in this path

    // L0 weights stay GLOBAL (12 KB, L1-resident, shared by all blocks on CU)
    const _Float16* bp0 = W16f + quad * 1536 + ln * 8;         // (kb=quad)*192 rows
    const int tile0 = (blockIdx.x - NB_B) * 4;

    #pragma unroll 1
    for (int tt = 0; tt < 4; ++tt) {
        // defeat LICM: force all loop-invariant loads to stay inside the loop
        // (r8 lesson: hoisting them ballooned VGPR 40->188, occupancy 61->11%)
        asm volatile("" ::: "memory");

        const int cid = (tile0 + tt) * 64 + w * 16 + ln;

        // x fragment for inst=ln, k-chunk quad
        half8 xfr;
        {
            const float* xp = X + (size_t)cid * F_INP + quad * 8;
            xfr = cvt8(*(const float4*)xp, *(const float4*)(xp + 4));
        }
        const float yv = y[cid];

        // L0: outputs written STRAIGHT into the L1 B-fragments (pi-permuted
        // weights make the lane's own 16 h1 values its fragment; no exchange).
        half8 a0, a1;
        #pragma unroll
        for (int jt = 0; jt < 4; ++jt) {
            // bias init from resident LDS (f32, prescaled, embed-bias folded)
            floatx4 ai = *(const floatx4*)(sh.A.b1cb + jt * 16 + quad * 4);
            floatx4 ag = *(const floatx4*)(sh.A.b1cb + 64 + jt * 16 + quad * 4);
            floatx4 ao = *(const floatx4*)(sh.A.b1cb + 128 + jt * 16 + quad * 4);
            ai = __builtin_amdgcn_mfma_f32_16x16x32_f16(*(const half8*)(bp0 + jt * 128),        xfr, ai, 0, 0, 0);
            ag = __builtin_amdgcn_mfma_f32_16x16x32_f16(*(const half8*)(bp0 + 512 + jt * 128),  xfr, ag, 0, 0, 0);
            ao = __builtin_amdgcn_mfma_f32_16x16x32_f16(*(const half8*)(bp0 + 1024 + jt * 128), xfr, ao, 0, 0, 0);
            // rank-1 y fold (f32)
            const floatx4 wyi = *(const floatx4*)(sh.A.wy1b + jt * 16 + quad * 4);
            const floatx4 wyg = *(const floatx4*)(sh.A.wy1b + 64 + jt * 16 + quad * 4);
            const floatx4 wyo = *(const floatx4*)(sh.A.wy1b + 128 + jt * 16 + quad * 4);
            a0[2 * jt + 0] = (_Float16)lstm_h(fmaf(yv, wyi[0], ai[0]),
                                              fmaf(yv, wyg[0], ag[0]),
                                              fmaf(yv, wyo[0], ao[0]));
            a0[2 * jt + 1] = (_Float16)lstm_h(fmaf(yv, wyi[1], ai[1]),
                                              fmaf(yv, wyg[1], ag[1]),
                                              fmaf(yv, wyo[1], ao[1]));
            a1[2 * jt + 0] = (_Float16)lstm_h(fmaf(yv, wyi[2], ai[2]),
                                              fmaf(yv, wyg[2], ag[2]),
                                              fmaf(yv, wyo[2], ao[2]));
            a1[2 * jt + 1] = (_Float16)lstm_h(fmaf(yv, wyi[3], ai[3]),
                                              fmaf(yv, wyg[3], ag[3]),
                                              fmaf(yv, wyo[3], ao[3]));
        }

        // ---- L1 in two phases from resident LDS (no staging, no barriers) ----
        float pm = 0.f, ps = 0.f;
        #pragma unroll
        for (int h = 0; h < 2; ++h) {
            const _Float16* bp = sh.A.Wlh[h] + quad * 768 + ln * 8;  // kb=quad (96 rows)
            #pragma unroll
            for (int jtl = 0; jtl < 2; ++jtl) {
                const int jt = h * 2 + jtl;
                floatx4 ai = *(const floatx4*)(sh.A.bs1b + jt * 16 + quad * 4);
                floatx4 ag = *(const floatx4*)(sh.A.bs1b + 64 + jt * 16 + quad * 4);
                floatx4 ao = *(const floatx4*)(sh.A.bs1b + 128 + jt * 16 + quad * 4);
                ai = __builtin_amdgcn_mfma_f32_16x16x32_f16(*(const half8*)(bp + jtl * 128),               a0, ai, 0, 0, 0);
                ai = __builtin_amdgcn_mfma_f32_16x16x32_f16(*(const half8*)(bp + jtl * 128 + 3072),        a1, ai, 0, 0, 0);
                ag = __builtin_amdgcn_mfma_f32_16x16x32_f16(*(const half8*)(bp + 256 + jtl * 128),         a0, ag, 0, 0, 0);
                ag = __builtin_amdgcn_mfma_f32_16x16x32_f16(*(const half8*)(bp + 256 + jtl * 128 + 3072),  a1, ag, 0, 0, 0);
                ao = __builtin_amdgcn_mfma_f32_16x16x32_f16(*(const half8*)(bp + 512 + jtl * 128),         a0, ao, 0, 0, 0);
                ao = __builtin_amdgcn_mfma_f32_16x16x32_f16(*(const half8*)(bp + 512 + jtl * 128 + 3072),  a1, ao, 0, 0, 0);
                // head partials in-thread: rows hid = jt*16+quad*4+r, inst = ln
                // W_mu/W_sigma global-direct (512 B, L1-resident)
                const floatx4 wm  = *(const floatx4*)(W_mu + jt * 16 + quad * 4);
                const floatx4 ws4 = *(const floatx4*)(W_sigma + jt * 16 + quad * 4);
                #pragma unroll
                for (int r = 0; r < 4; ++r) {
                    const float hr = fmaxf(lstm_h(ai[r], ag[r], ao[r]), 0.0f);
                    pm = fmaf(hr, wm[r], pm);
                    ps = fmaf(hr, ws4[r], ps);
                }
            }
        }

        // reduce over quads only (hid split across quads; inst=ln is lane-local)
        pm += __shfl_xor(pm, 16, 64); pm += __shfl_xor(pm, 32, 64);
        ps += __shfl_xor(ps, 16, 64); ps += __shfl_xor(ps, 32, 64);

        if (quad == 0) {
            const int n = cid / SEQ;
            const int t = cid - n * SEQ;
            const float mu = pm + b_mu[0];
            const float sg = softplus_(ps + b_sigma[0]) + 1e-6f;
            mu_out[(size_t)n * T_ALL + t] = mu;
            sg_out[(size_t)n * T_ALL + t] = sg;
            if (t == SEQ - 1) {
                const float d  = yv - mu;
                const float is = frcp(sg);
                out[(size_t)n * HOR] = 0.39894228040143267f * is * fexp(-0.5f * d * d * is * is);
            }
        }
    }
}

extern "C" void kernel_launch(void* const* d_in, const int* in_sizes, int n_in,
                              void* d_out, int out_size, void* d_ws, size_t ws_size,
                              hipStream_t stream) {
    const float* X       = (const float*)d_in[0];
    const float* y       = (const float*)d_in[1];
    const float* Xf      = (const float*)d_in[2];
    const float* W_embed = (const float*)d_in[3];
    const float* b_embed = (const float*)d_in[4];
    const float* W_ih    = (const float*)d_in[5];
    const float* b_ih    = (const float*)d_in[6];
    const float* b_hh    = (const float*)d_in[7];
    const float* W_mu    = (const float*)d_in[8];
    const float* b_mu    = (const float*)d_in[9];
    const float* W_sigma = (const float*)d_in[10];
    const float* b_sigma = (const float*)d_in[11];

    float* out = (float*)d_out;
    // ws: W16f(61440 B: L0 12KB + L1std 24KB + L1perm 24KB) | bsum(1536) | wy1(768) | b1c(768)
    _Float16*  W16f = (_Float16*)d_ws;
    float*     bsum = (float*)((char*)d_ws + 61440);
    float*     wy1  = (float*)((char*)d_ws + 61440 + 1536);
    float*     b1c  = (float*)((char*)d_ws + 61440 + 1536 + 768);

    prep<<<96, 256, 0, stream>>>(W_ih, b_ih, b_hh, W_embed, b_embed,
                                 W16f, bsum, wy1, b1c);

    fused<<<NB_B + NT_B, 256, 0, stream>>>(
        X, y, Xf, W_embed, b_embed, W16f, bsum, wy1, b1c,
        W_mu, b_mu, W_sigma, b_sigma, out);
}

// Round 11
// 230.407 us; speedup vs baseline: 1.0912x; 1.0912x over previous
//
#include <hip/hip_runtime.h>
#include <math.h>

#define N_TS 4096
#define SEQ  168
#define HOR  24
#define T_ALL 192
#define F_INP 32
#define HID  64
#define NROW 192            // compacted gate rows: i(64) g(64) o(64)
#define NB_B (N_TS / 16)    // 256 autoregressive blocks (16 series each)
#define NT_B ((N_TS * SEQ) / 256)  // 2688 teacher blocks (4 tiles x 64 instances)
#define L2E  1.44269504089f
#define W16F_L1  6144       // half-offset of standard layer-1 weights (AR path)
#define W16F_L1P 18432      // half-offset of PHASE-MAJOR permuted layer-1 weights

typedef _Float16 half8  __attribute__((ext_vector_type(8)));
typedef _Float16 half4  __attribute__((ext_vector_type(4)));
typedef float    floatx4 __attribute__((ext_vector_type(4)));

__device__ __forceinline__ float fexp(float x)  { return __expf(x); }
__device__ __forceinline__ float ex2(float x)   { return __builtin_amdgcn_exp2f(x); }
__device__ __forceinline__ float frcp(float x)  { return __builtin_amdgcn_rcpf(x); }
__device__ __forceinline__ float softplus_(float x) { return (x > 15.0f) ? x : __logf(1.0f + fexp(x)); }

// Gates arrive PRESCALED: i,o rows x(-log2e); g rows x(-2*log2e) — folded into
// weights/biases, so every sigmoid/tanh exp is a bare v_exp (2^x).
// Exact form (AR path): 6 transcendentals.
__device__ __forceinline__ float lstm_h(float ip, float gp, float op) {
    const float Ei = ex2(ip);
    const float Eg = ex2(gp);
    const float cc = (1.0f - Eg) * frcp((1.0f + Ei) * (1.0f + Eg));
    const float Ec = ex2(cc * (-2.0f * L2E));
    const float Eo = ex2(op);
    return (1.0f - Ec) * frcp((1.0f + Ec) * (1.0f + Eo));
}

// Fast form (teacher path): tanh(c) via Pade [3/2] x(15+x^2)/(15+6x^2)
// (|c|<1 strictly, max err 3.1e-4), c kept as ratio A/B so ONE rcp total.
// 4 transcendentals (3 exp + 1 rcp) vs 6. The 1/64 common scale on A,B is
// an identity that pushes den overflow out to ~14-sigma gate tails.
__device__ __forceinline__ float lstm_h_fast(float ip, float gp, float op) {
    const float Ei = ex2(ip);
    const float Eg = ex2(gp);
    const float Eo = ex2(op);
    const float A  = 0.015625f * (1.0f - Eg);
    const float B  = 0.015625f * ((1.0f + Ei) * (1.0f + Eg));
    const float A2 = A * A;
    const float B2 = B * B;
    const float t15 = 15.0f * B2;
    const float num = A * (t15 + A2);
    const float den = B * fmaf(6.0f, A2, t15) * (1.0f + Eo);
    return num * frcp(den);
}

__device__ __forceinline__ half8 cvt8(const float4 a, const float4 b) {
    half8 v;
    v[0]=(_Float16)a.x; v[1]=(_Float16)a.y; v[2]=(_Float16)a.z; v[3]=(_Float16)a.w;
    v[4]=(_Float16)b.x; v[5]=(_Float16)b.y; v[6]=(_Float16)b.z; v[7]=(_Float16)b.w;
    return v;
}

// ---------------------------------------------------------------------------
// prep: compacted (f dropped), PRESCALED weights in k-chunked fragment layout
//   layer 0 (x-cols only, k<32): W16f[(kb*192+row)*8+kp], kb in [0,4)
//   layer 1 standard (AR path):  W16f[W16F_L1 + (kb*192+row)*8+kp], k = hid
//   layer 1 permuted PHASE-MAJOR (teacher): W16F_L1P +
//       h*6144 + ((kb*96 + gate*32 + jtl*16 + r16)*8 + kp), jt = h*2+jtl,
//     column k = pi(hid):  k=q*8+2*d+e     <-> hid=d*16+q*4+e      (k < 32)
//                          k=32+q*8+2*d+e  <-> hid=d*16+q*4+2+e    (k >= 32)
//   so the teacher's own L0 output registers ARE its L1 B-fragment (no exchange),
//   and each 12 KB phase-half is self-contained (all gates, both k-halves).
// Rank-1 embed fold (prescaled): wy1 = W1[:,32:]@W_embed ; b1c = b1 + W1[:,32:]@b_embed.
// ---------------------------------------------------------------------------
__global__ __launch_bounds__(256) void prep(
    const float* __restrict__ W_ih, const float* __restrict__ b_ih,
    const float* __restrict__ b_hh,
    const float* __restrict__ W_embed, const float* __restrict__ b_embed,
    _Float16* __restrict__ W16f, float* __restrict__ bsum,
    float* __restrict__ wy1, float* __restrict__ b1c)
{
    const int idx = blockIdx.x * 256 + threadIdx.x;
    // layer 0: x-cols only
    for (int i = idx; i < 4 * NROW * 8; i += gridDim.x * 256) {
        const int kp  = i & 7;
        const int row = (i >> 3) % NROW;
        const int kb  = (i >> 3) / NROW;                   // 0..3 -> k = kb*8+kp < 32
        const int sr  = (row < 64) ? row : row + 64;       // skip dead f rows
        const float sc = (row >= 64 && row < 128) ? (-2.0f * L2E) : (-L2E);
        W16f[i] = (_Float16)(W_ih[sr * HID + kb * 8 + kp] * sc);
    }
    // layer 1 standard (k = hid identity) — AR path
    for (int i = idx; i < 8 * NROW * 8; i += gridDim.x * 256) {
        const int kp  = i & 7;
        const int row = (i >> 3) % NROW;
        const int kb  = (i >> 3) / NROW;                   // 0..7
        const int sr  = (row < 64) ? row : row + 64;
        const float sc = (row >= 64 && row < 128) ? (-2.0f * L2E) : (-L2E);
        W16f[W16F_L1 + i] = (_Float16)(W_ih[(256 + sr) * HID + kb * 8 + kp] * sc);
    }
    // layer 1 permuted, phase-major (teacher)
    for (int i = idx; i < 2 * 6144; i += gridDim.x * 256) {
        const int h    = i / 6144;
        const int rem  = i - h * 6144;
        const int kp   = rem & 7;
        const int t    = rem >> 3;                         // 0..767
        const int rowb = t % 96;
        const int kb   = t / 96;                           // 0..7
        const int gate = rowb >> 5;                        // 0:i 1:g 2:o
        const int jtl  = (rowb >> 4) & 1;
        const int r16  = rowb & 15;
        const int jt   = h * 2 + jtl;
        const int srow = gate * 64 + jt * 16 + r16;        // compacted row 0..191
        const int sr   = (srow < 64) ? srow : srow + 64;   // skip dead f rows
        const int k    = kb * 8 + kp;                      // logical k = pi(hid)
        const int kk   = k & 31;
        const int d    = (kk >> 1) & 3;
        const int q    = kk >> 3;
        const int e    = kk & 1;
        const int hid  = d * 16 + q * 4 + ((k >> 5) << 1) + e;
        const float sc = (gate == 1) ? (-2.0f * L2E) : (-L2E);
        W16f[W16F_L1P + i] = (_Float16)(W_ih[(256 + sr) * HID + hid] * sc);
    }
    for (int i = idx; i < 2 * NROW; i += gridDim.x * 256) {
        const int r = i % NROW;
        const int l = i / NROW;
        const int sr = (r < 64) ? r : r + 64;
        const float sc = (r >= 64 && r < 128) ? (-2.0f * L2E) : (-L2E);
        bsum[i] = (b_ih[l * 256 + sr] + b_hh[l * 256 + sr]) * sc;
    }
    if (idx < NROW) {
        const int sr = (idx < 64) ? idx : idx + 64;
        const float sc = (idx >= 64 && idx < 128) ? (-2.0f * L2E) : (-L2E);
        const float* wrow = W_ih + sr * HID + 32;          // layer 0, cols 32..63
        float s1 = 0.f, s2 = 0.f;
        #pragma unroll
        for (int k = 0; k < 32; ++k) {
            s1 = fmaf(wrow[k], W_embed[k], s1);
            s2 = fmaf(wrow[k], b_embed[k], s2);
        }
        wy1[idx] = s1 * sc;
        b1c[idx] = (b_ih[sr] + b_hh[sr] + s2) * sc;
    }
}

// ---------------------------------------------------------------------------
// fused, 256-thread blocks (4 waves):
//  blocks [0, NB_B): autoregressive path — proven 16-series form, persistent
//   register fragments, XOR-swizzled slab, 2 barriers/step. EXACT lstm_h.
//  blocks [NB_B, ...): teacher path (r9 structure, 117 us): stage ALL weights
//   + bias/head vectors once (39.7 KB), ONE barrier, then 4 barrier-free
//   staging-free tiles; memory clobber per tile defeats LICM (r8: VGPR 188).
//   lstm_h_fast (4 trans) — trans pipe was ~2/3 of teacher issue time.
//  LDS union = 39680 B -> 4 blocks/CU (16 waves/CU), VGPR ~56.
// ---------------------------------------------------------------------------
__global__ __launch_bounds__(256, 6) void fused(
    const float* __restrict__ X,
    const float* __restrict__ y,
    const float* __restrict__ Xf,
    const float* __restrict__ W_embed,
    const float* __restrict__ b_embed,
    const _Float16* __restrict__ W16f,
    const float* __restrict__ bsum,
    const float* __restrict__ wy1,
    const float* __restrict__ b1c,
    const float* __restrict__ W_mu,
    const float* __restrict__ b_mu,
    const float* __restrict__ W_sigma,
    const float* __restrict__ b_sigma,
    float* __restrict__ out)
{
    __shared__ union __align__(16) {
        struct {                                           // teacher: 39680 B
            _Float16 Wl0[6144]; _Float16 Wlh[2][6144];
            float b1cb[NROW]; float wy1b[NROW]; float bs1b[NROW];
            float wmb[HID]; float wsb[HID];
        } A;
        struct { _Float16 slab[16 * 64]; float partm[16][4]; float parts[16][4];
                 float wyb[NROW]; float b1cb[NROW]; } B;                 // ~4.1 KB
    } sh;

    const int tid = threadIdx.x;
    float* mu_out = out + (size_t)N_TS * HOR;
    float* sg_out = mu_out + (size_t)N_TS * T_ALL;

    if (blockIdx.x < NB_B) {
        // =================== autoregressive path (4 waves) ===================
        __builtin_amdgcn_s_setprio(1);           // beat co-resident teacher waves
        const int w    = tid >> 6;
        const int lane = tid & 63;
        const int quad = lane >> 4;
        const int ln   = lane & 15;
        const int n0   = blockIdx.x * 16;

        if (tid < NROW) {
            sh.B.wyb[tid]  = wy1[tid];
            sh.B.b1cb[tid] = b1c[tid];
        }

        // persistent register fragments (wave w owns row-tiles rt = j*4+w)
        half8 B1[3];        // W1 rows, k<32 (embed cols via rank-1 fold)
        half8 B2[3][2];     // W2 rows, full k (STANDARD layout)
        float bias2[3];
        #pragma unroll
        for (int j = 0; j < 3; ++j) {
            const int rt = j * 4 + w;
            B1[j] = *(const half8*)(W16f + ((size_t)quad * NROW + rt * 16 + ln) * 8);
            #pragma unroll
            for (int kt = 0; kt < 2; ++kt)
                B2[j][kt] = *(const half8*)(W16f + W16F_L1 + ((size_t)(kt * 4 + quad) * NROW + rt * 16 + ln) * 8);
            bias2[j] = bsum[NROW + rt * 16 + ln];
        }
        const float wmu = W_mu[w * 16 + ln], wsg = W_sigma[w * 16 + ln];
        const float bmu = b_mu[0], bsg = b_sigma[0];

        // bootstrap inputs: t = 167
        const float* xfp = Xf + (size_t)(n0 + ln) * HOR * F_INP + quad * 8;
        float4 xa, xb;
        {
            const float* xp = X + ((size_t)(n0 + ln) * SEQ + (SEQ - 1)) * F_INP + quad * 8;
            xa = *(const float4*)xp;
            xb = *(const float4*)(xp + 4);
        }
        float ycur = y[(size_t)(n0 + ln) * SEQ + (SEQ - 1)];
        __syncthreads();                         // wyb/b1cb visible

        #pragma unroll 1
        for (int it = 0; it <= HOR + 1; ++it) {
            if (it > 0) {
                // finalize step k = it-1 (redundant per-lane, bit-identical)
                const int k = it - 1;
                const float4 m4 = *(const float4*)sh.B.partm[ln];
                const float4 s4 = *(const float4*)sh.B.parts[ln];
                const float mu = (m4.x + m4.y) + (m4.z + m4.w) + bmu;
                const float sg = softplus_((s4.x + s4.y) + (s4.z + s4.w) + bsg) + 1e-6f;
                const float d  = ycur - mu;
                const float is = frcp(sg);
                const float lik = 0.39894228040143267f * is * fexp(-0.5f * d * d * is * is);
                if (k > 0 && w == 0 && quad == 0) {
                    const int nn = n0 + ln;
                    const int t  = SEQ + k - 1;
                    mu_out[(size_t)nn * T_ALL + t] = mu;
                    sg_out[(size_t)nn * T_ALL + t] = sg;
                    if (k < HOR) out[(size_t)nn * HOR + k] = lik;
                }
                ycur = lik;
            }
            if (it > HOR) break;

            // ---- compute step it (input carry = ycur) ----
            const half8 xf0 = cvt8(xa, xb);
            if (it < HOR) {                      // next iter uses Xf step it
                xa = *(const float4*)(xfp + it * F_INP);
                xb = *(const float4*)(xfp + it * F_INP + 4);
            }

            // layer 1: 3 MFMAs; C row = unit-in-tile (quad*4+r), col = series(ln)
            floatx4 t0 = *(const floatx4*)(sh.B.b1cb + 0 * 64 + w * 16 + quad * 4);
            floatx4 t1 = *(const floatx4*)(sh.B.b1cb + 1 * 64 + w * 16 + quad * 4);
            floatx4 t2 = *(const floatx4*)(sh.B.b1cb + 2 * 64 + w * 16 + quad * 4);
            t0 = __builtin_amdgcn_mfma_f32_16x16x32_f16(B1[0], xf0, t0, 0, 0, 0);
            t1 = __builtin_amdgcn_mfma_f32_16x16x32_f16(B1[1], xf0, t1, 0, 0, 0);
            t2 = __builtin_amdgcn_mfma_f32_16x16x32_f16(B1[2], xf0, t2, 0, 0, 0);

            const floatx4 wy0  = *(const floatx4*)(sh.B.wyb + 0 * 64 + w * 16 + quad * 4);
            const floatx4 wy1v = *(const floatx4*)(sh.B.wyb + 1 * 64 + w * 16 + quad * 4);
            const floatx4 wy2  = *(const floatx4*)(sh.B.wyb + 2 * 64 + w * 16 + quad * 4);

            half4 h1p;
            #pragma unroll
            for (int r = 0; r < 4; ++r) {
                const float ig = fmaf(ycur, wy0[r],  t0[r]);
                const float gg = fmaf(ycur, wy1v[r], t1[r]);
                const float og = fmaf(ycur, wy2[r],  t2[r]);
                h1p[r] = (_Float16)lstm_h(ig, gg, og);
            }
            // XOR-swizzled slab write: unit 16B-block = 2*w + (quad>>1)
            {
                const int xblk = (2 * w + (quad >> 1)) ^ (ln & 7);
                *(half4*)(&sh.B.slab[ln * 64 + xblk * 8 + (quad & 1) * 4]) = h1p;
            }
            __syncthreads();

            // layer 2: A = h1 series-frag (swizzled reads)
            const half8 a0 = *(const half8*)(&sh.B.slab[ln * 64 + ((quad ^ (ln & 7)) << 3)]);
            const half8 a1 = *(const half8*)(&sh.B.slab[ln * 64 + (((4 + quad) ^ (ln & 7)) << 3)]);
            floatx4 acc[3];
            #pragma unroll
            for (int j = 0; j < 3; ++j) {
                acc[j] = (floatx4){bias2[j], bias2[j], bias2[j], bias2[j]};
                acc[j] = __builtin_amdgcn_mfma_f32_16x16x32_f16(a0, B2[j][0], acc[j], 0, 0, 0);
                acc[j] = __builtin_amdgcn_mfma_f32_16x16x32_f16(a1, B2[j][1], acc[j], 0, 0, 0);
            }

            // act L2 + head partials: unit w*16+ln, series quad*4+r
            float pmr[4], psr[4];
            #pragma unroll
            for (int r = 0; r < 4; ++r) {
                const float hh = lstm_h(acc[0][r], acc[1][r], acc[2][r]);
                const float hr = fmaxf(hh, 0.0f);
                pmr[r] = hr * wmu;
                psr[r] = hr * wsg;
            }
            #pragma unroll
            for (int off = 1; off < 16; off <<= 1) {
                #pragma unroll
                for (int r = 0; r < 4; ++r) {
                    pmr[r] += __shfl_xor(pmr[r], off, 64);
                    psr[r] += __shfl_xor(psr[r], off, 64);
                }
            }
            if (ln == 0) {
                #pragma unroll
                for (int r = 0; r < 4; ++r) {
                    sh.B.partm[quad * 4 + r][w] = pmr[r];
                    sh.B.parts[quad * 4 + r][w] = psr[r];
                }
            }
            __syncthreads();
        }
        return;
    }

    // ======================= teacher-forced path (4 waves) =======================
    const int w    = tid >> 6;
    const int lane = tid & 63;
    const int quad = lane >> 4;
    const int ln   = lane & 15;

    // ---- one-time stage: L0 (12K) + both L1P halves (24K) + bias/head vecs ----
    #pragma unroll
    for (int c = 0; c < 3; ++c) {
        const int off = (c * 256 + tid) * 8;
        *(half8*)(sh.A.Wl0 + off)    = *(const half8*)(W16f + off);
        *(half8*)(sh.A.Wlh[0] + off) = *(const half8*)(W16f + W16F_L1P + off);
        *(half8*)(sh.A.Wlh[1] + off) = *(const half8*)(W16f + W16F_L1P + 6144 + off);
    }
    if (tid < NROW) {
        sh.A.b1cb[tid] = b1c[tid];
        sh.A.wy1b[tid] = wy1[tid];
        sh.A.bs1b[tid] = bsum[NROW + tid];
    }
    if (tid < HID) { sh.A.wmb[tid] = W_mu[tid]; sh.A.wsb[tid] = W_sigma[tid]; }
    __syncthreads();                 // the ONLY barrier in this path

    const _Float16* bp0 = sh.A.Wl0 + quad * 1536 + ln * 8;     // (kb=quad)*192 rows
    const int tile0 = (blockIdx.x - NB_B) * 4;

    #pragma unroll 1
    for (int tt = 0; tt < 4; ++tt) {
        // defeat LICM: force all loop-invariant loads to stay inside the loop
        // (r8 lesson: hoisting them ballooned VGPR 40->188, occupancy 61->11%)
        asm volatile("" ::: "memory");

        const int cid = (tile0 + tt) * 64 + w * 16 + ln;

        // x fragment for inst=ln, k-chunk quad
        half8 xfr;
        {
            const float* xp = X + (size_t)cid * F_INP + quad * 8;
            xfr = cvt8(*(const float4*)xp, *(const float4*)(xp + 4));
        }
        const float yv = y[cid];

        // L0: outputs written STRAIGHT into the L1 B-fragments (pi-permuted
        // weights make the lane's own 16 h1 values its fragment; no exchange).
        half8 a0, a1;
        #pragma unroll
        for (int jt = 0; jt < 4; ++jt) {
            // bias init from resident LDS (f32, prescaled, embed-bias folded)
            floatx4 ai = *(const floatx4*)(sh.A.b1cb + jt * 16 + quad * 4);
            floatx4 ag = *(const floatx4*)(sh.A.b1cb + 64 + jt * 16 + quad * 4);
            floatx4 ao = *(const floatx4*)(sh.A.b1cb + 128 + jt * 16 + quad * 4);
            ai = __builtin_amdgcn_mfma_f32_16x16x32_f16(*(const half8*)(bp0 + jt * 128),        xfr, ai, 0, 0, 0);
            ag = __builtin_amdgcn_mfma_f32_16x16x32_f16(*(const half8*)(bp0 + 512 + jt * 128),  xfr, ag, 0, 0, 0);
            ao = __builtin_amdgcn_mfma_f32_16x16x32_f16(*(const half8*)(bp0 + 1024 + jt * 128), xfr, ao, 0, 0, 0);
            // rank-1 y fold (f32)
            const floatx4 wyi = *(const floatx4*)(sh.A.wy1b + jt * 16 + quad * 4);
            const floatx4 wyg = *(const floatx4*)(sh.A.wy1b + 64 + jt * 16 + quad * 4);
            const floatx4 wyo = *(const floatx4*)(sh.A.wy1b + 128 + jt * 16 + quad * 4);
            a0[2 * jt + 0] = (_Float16)lstm_h_fast(fmaf(yv, wyi[0], ai[0]),
                                                   fmaf(yv, wyg[0], ag[0]),
                                                   fmaf(yv, wyo[0], ao[0]));
            a0[2 * jt + 1] = (_Float16)lstm_h_fast(fmaf(yv, wyi[1], ai[1]),
                                                   fmaf(yv, wyg[1], ag[1]),
                                                   fmaf(yv, wyo[1], ao[1]));
            a1[2 * jt + 0] = (_Float16)lstm_h_fast(fmaf(yv, wyi[2], ai[2]),
                                                   fmaf(yv, wyg[2], ag[2]),
                                                   fmaf(yv, wyo[2], ao[2]));
            a1[2 * jt + 1] = (_Float16)lstm_h_fast(fmaf(yv, wyi[3], ai[3]),
                                                   fmaf(yv, wyg[3], ag[3]),
                                                   fmaf(yv, wyo[3], ao[3]));
        }

        // ---- L1 in two phases from resident LDS (no staging, no barriers) ----
        float pm = 0.f, ps = 0.f;
        #pragma unroll
        for (int h = 0; h < 2; ++h) {
            const _Float16* bp = sh.A.Wlh[h] + quad * 768 + ln * 8;  // kb=quad (96 rows)
            #pragma unroll
            for (int jtl = 0; jtl < 2; ++jtl) {
                const int jt = h * 2 + jtl;
                floatx4 ai = *(const floatx4*)(sh.A.bs1b + jt * 16 + quad * 4);
                floatx4 ag = *(const floatx4*)(sh.A.bs1b + 64 + jt * 16 + quad * 4);
                floatx4 ao = *(const floatx4*)(sh.A.bs1b + 128 + jt * 16 + quad * 4);
                ai = __builtin_amdgcn_mfma_f32_16x16x32_f16(*(const half8*)(bp + jtl * 128),               a0, ai, 0, 0, 0);
                ai = __builtin_amdgcn_mfma_f32_16x16x32_f16(*(const half8*)(bp + jtl * 128 + 3072),        a1, ai, 0, 0, 0);
                ag = __builtin_amdgcn_mfma_f32_16x16x32_f16(*(const half8*)(bp + 256 + jtl * 128),         a0, ag, 0, 0, 0);
                ag = __builtin_amdgcn_mfma_f32_16x16x32_f16(*(const half8*)(bp + 256 + jtl * 128 + 3072),  a1, ag, 0, 0, 0);
                ao = __builtin_amdgcn_mfma_f32_16x16x32_f16(*(const half8*)(bp + 512 + jtl * 128),         a0, ao, 0, 0, 0);
                ao = __builtin_amdgcn_mfma_f32_16x16x32_f16(*(const half8*)(bp + 512 + jtl * 128 + 3072),  a1, ao, 0, 0, 0);
                // head partials in-thread: rows hid = jt*16+quad*4+r, inst = ln
                const floatx4 wm  = *(const floatx4*)(sh.A.wmb + jt * 16 + quad * 4);
                const floatx4 ws4 = *(const floatx4*)(sh.A.wsb + jt * 16 + quad * 4);
                #pragma unroll
                for (int r = 0; r < 4; ++r) {
                    const float hr = fmaxf(lstm_h_fast(ai[r], ag[r], ao[r]), 0.0f);
                    pm = fmaf(hr, wm[r], pm);
                    ps = fmaf(hr, ws4[r], ps);
                }
            }
        }

        // reduce over quads only (hid split across quads; inst=ln is lane-local)
        pm += __shfl_xor(pm, 16, 64); pm += __shfl_xor(pm, 32, 64);
        ps += __shfl_xor(ps, 16, 64); ps += __shfl_xor(ps, 32, 64);

        if (quad == 0) {
            const int n = cid / SEQ;
            const int t = cid - n * SEQ;
            const float mu = pm + b_mu[0];
            const float sg = softplus_(ps + b_sigma[0]) + 1e-6f;
            mu_out[(size_t)n * T_ALL + t] = mu;
            sg_out[(size_t)n * T_ALL + t] = sg;
            if (t == SEQ - 1) {
                const float d  = yv - mu;
                const float is = frcp(sg);
                out[(size_t)n * HOR] = 0.39894228040143267f * is * fexp(-0.5f * d * d * is * is);
            }
        }
    }
}

extern "C" void kernel_launch(void* const* d_in, const int* in_sizes, int n_in,
                              void* d_out, int out_size, void* d_ws, size_t ws_size,
                              hipStream_t stream) {
    const float* X       = (const float*)d_in[0];
    const float* y       = (const float*)d_in[1];
    const float* Xf      = (const float*)d_in[2];
    const float* W_embed = (const float*)d_in[3];
    const float* b_embed = (const float*)d_in[4];
    const float* W_ih    = (const float*)d_in[5];
    const float* b_ih    = (const float*)d_in[6];
    const float* b_hh    = (const float*)d_in[7];
    const float* W_mu    = (const float*)d_in[8];
    const float* b_mu    = (const float*)d_in[9];
    const float* W_sigma = (const float*)d_in[10];
    const float* b_sigma = (const float*)d_in[11];

    float* out = (float*)d_out;
    // ws: W16f(61440 B: L0 12KB + L1std 24KB + L1perm 24KB) | bsum(1536) | wy1(768) | b1c(768)
    _Float16*  W16f = (_Float16*)d_ws;
    float*     bsum = (float*)((char*)d_ws + 61440);
    float*     wy1  = (float*)((char*)d_ws + 61440 + 1536);
    float*     b1c  = (float*)((char*)d_ws + 61440 + 1536 + 768);

    prep<<<96, 256, 0, stream>>>(W_ih, b_ih, b_hh, W_embed, b_embed,
                                 W16f, bsum, wy1, b1c);

    fused<<<NB_B + NT_B, 256, 0, stream>>>(
        X, y, Xf, W_embed, b_embed, W16f, bsum, wy1, b1c,
        W_mu, b_mu, W_sigma, b_sigma, out);
}

// Round 12
// 228.560 us; speedup vs baseline: 1.1000x; 1.0081x over previous
//
#include <hip/hip_runtime.h>
#include <math.h>

#define N_TS 4096
#define SEQ  168
#define HOR  24
#define T_ALL 192
#define F_INP 32
#define HID  64
#define NROW 192            // compacted gate rows: i(64) g(64) o(64)
#define NB_B (N_TS / 16)    // 256 autoregressive blocks (16 series each)
#define NT_B ((N_TS * SEQ) / 256)  // 2688 teacher blocks (4 tiles x 64 instances)
#define L2E  1.44269504089f
#define W16F_L1  6144       // half-offset of standard layer-1 weights (AR path)
#define W16F_L1P 18432      // half-offset of PHASE-MAJOR permuted layer-1 weights

typedef _Float16 half8  __attribute__((ext_vector_type(8)));
typedef _Float16 half4  __attribute__((ext_vector_type(4)));
typedef float    floatx4 __attribute__((ext_vector_type(4)));

__device__ __forceinline__ float fexp(float x)  { return __expf(x); }
__device__ __forceinline__ float ex2(float x)   { return __builtin_amdgcn_exp2f(x); }
__device__ __forceinline__ float frcp(float x)  { return __builtin_amdgcn_rcpf(x); }
__device__ __forceinline__ float softplus_(float x) { return (x > 15.0f) ? x : __logf(1.0f + fexp(x)); }

// Gates arrive PRESCALED: i,o rows x(-log2e); g rows x(-2*log2e) — folded into
// weights/biases, so every sigmoid/tanh exp is a bare v_exp (2^x).
// Exact form (AR path): 6 transcendentals.
__device__ __forceinline__ float lstm_h(float ip, float gp, float op) {
    const float Ei = ex2(ip);
    const float Eg = ex2(gp);
    const float cc = (1.0f - Eg) * frcp((1.0f + Ei) * (1.0f + Eg));
    const float Ec = ex2(cc * (-2.0f * L2E));
    const float Eo = ex2(op);
    return (1.0f - Ec) * frcp((1.0f + Ec) * (1.0f + Eo));
}

// Fast form (teacher path): tanh(c) via Pade [3/2] x(15+x^2)/(15+6x^2)
// (|c|<1 strictly, max err 3.1e-4), c kept as ratio A/B so ONE rcp total.
// r11 measured: same speed as exact (exp2 is ~VALU-rate), same absmax — kept.
__device__ __forceinline__ float lstm_h_fast(float ip, float gp, float op) {
    const float Ei = ex2(ip);
    const float Eg = ex2(gp);
    const float Eo = ex2(op);
    const float A  = 0.015625f * (1.0f - Eg);
    const float B  = 0.015625f * ((1.0f + Ei) * (1.0f + Eg));
    const float A2 = A * A;
    const float B2 = B * B;
    const float t15 = 15.0f * B2;
    const float num = A * (t15 + A2);
    const float den = B * fmaf(6.0f, A2, t15) * (1.0f + Eo);
    return num * frcp(den);
}

__device__ __forceinline__ half8 cvt8(const float4 a, const float4 b) {
    half8 v;
    v[0]=(_Float16)a.x; v[1]=(_Float16)a.y; v[2]=(_Float16)a.z; v[3]=(_Float16)a.w;
    v[4]=(_Float16)b.x; v[5]=(_Float16)b.y; v[6]=(_Float16)b.z; v[7]=(_Float16)b.w;
    return v;
}

// ---------------------------------------------------------------------------
// prep: compacted (f dropped), PRESCALED weights in k-chunked fragment layout
//   layer 0 (x-cols only, k<32): W16f[(kb*192+row)*8+kp], kb in [0,4)
//   layer 1 standard (AR path):  W16f[W16F_L1 + (kb*192+row)*8+kp], k = hid
//   layer 1 permuted PHASE-MAJOR (teacher): W16F_L1P +
//       h*6144 + ((kb*96 + gate*32 + jtl*16 + r16)*8 + kp), jt = h*2+jtl,
//     column k = pi(hid):  k=q*8+2*d+e     <-> hid=d*16+q*4+e      (k < 32)
//                          k=32+q*8+2*d+e  <-> hid=d*16+q*4+2+e    (k >= 32)
//   so the teacher's own L0 output registers ARE its L1 B-fragment (no exchange),
//   and each 12 KB phase-half is self-contained (all gates, both k-halves).
// Rank-1 embed fold (prescaled): wy1 = W1[:,32:]@W_embed ; b1c = b1 + W1[:,32:]@b_embed.
// ---------------------------------------------------------------------------
__global__ __launch_bounds__(256) void prep(
    const float* __restrict__ W_ih, const float* __restrict__ b_ih,
    const float* __restrict__ b_hh,
    const float* __restrict__ W_embed, const float* __restrict__ b_embed,
    _Float16* __restrict__ W16f, float* __restrict__ bsum,
    float* __restrict__ wy1, float* __restrict__ b1c)
{
    const int idx = blockIdx.x * 256 + threadIdx.x;
    // layer 0: x-cols only
    for (int i = idx; i < 4 * NROW * 8; i += gridDim.x * 256) {
        const int kp  = i & 7;
        const int row = (i >> 3) % NROW;
        const int kb  = (i >> 3) / NROW;                   // 0..3 -> k = kb*8+kp < 32
        const int sr  = (row < 64) ? row : row + 64;       // skip dead f rows
        const float sc = (row >= 64 && row < 128) ? (-2.0f * L2E) : (-L2E);
        W16f[i] = (_Float16)(W_ih[sr * HID + kb * 8 + kp] * sc);
    }
    // layer 1 standard (k = hid identity) — AR path
    for (int i = idx; i < 8 * NROW * 8; i += gridDim.x * 256) {
        const int kp  = i & 7;
        const int row = (i >> 3) % NROW;
        const int kb  = (i >> 3) / NROW;                   // 0..7
        const int sr  = (row < 64) ? row : row + 64;
        const float sc = (row >= 64 && row < 128) ? (-2.0f * L2E) : (-L2E);
        W16f[W16F_L1 + i] = (_Float16)(W_ih[(256 + sr) * HID + kb * 8 + kp] * sc);
    }
    // layer 1 permuted, phase-major (teacher)
    for (int i = idx; i < 2 * 6144; i += gridDim.x * 256) {
        const int h    = i / 6144;
        const int rem  = i - h * 6144;
        const int kp   = rem & 7;
        const int t    = rem >> 3;                         // 0..767
        const int rowb = t % 96;
        const int kb   = t / 96;                           // 0..7
        const int gate = rowb >> 5;                        // 0:i 1:g 2:o
        const int jtl  = (rowb >> 4) & 1;
        const int r16  = rowb & 15;
        const int jt   = h * 2 + jtl;
        const int srow = gate * 64 + jt * 16 + r16;        // compacted row 0..191
        const int sr   = (srow < 64) ? srow : srow + 64;   // skip dead f rows
        const int k    = kb * 8 + kp;                      // logical k = pi(hid)
        const int kk   = k & 31;
        const int d    = (kk >> 1) & 3;
        const int q    = kk >> 3;
        const int e    = kk & 1;
        const int hid  = d * 16 + q * 4 + ((k >> 5) << 1) + e;
        const float sc = (gate == 1) ? (-2.0f * L2E) : (-L2E);
        W16f[W16F_L1P + i] = (_Float16)(W_ih[(256 + sr) * HID + hid] * sc);
    }
    for (int i = idx; i < 2 * NROW; i += gridDim.x * 256) {
        const int r = i % NROW;
        const int l = i / NROW;
        const int sr = (r < 64) ? r : r + 64;
        const float sc = (r >= 64 && r < 128) ? (-2.0f * L2E) : (-L2E);
        bsum[i] = (b_ih[l * 256 + sr] + b_hh[l * 256 + sr]) * sc;
    }
    if (idx < NROW) {
        const int sr = (idx < 64) ? idx : idx + 64;
        const float sc = (idx >= 64 && idx < 128) ? (-2.0f * L2E) : (-L2E);
        const float* wrow = W_ih + sr * HID + 32;          // layer 0, cols 32..63
        float s1 = 0.f, s2 = 0.f;
        #pragma unroll
        for (int k = 0; k < 32; ++k) {
            s1 = fmaf(wrow[k], W_embed[k], s1);
            s2 = fmaf(wrow[k], b_embed[k], s2);
        }
        wy1[idx] = s1 * sc;
        b1c[idx] = (b_ih[sr] + b_hh[sr] + s2) * sc;
    }
}

// ---------------------------------------------------------------------------
// fused, 256-thread blocks (4 waves):
//  blocks [0, NB_B): autoregressive path — proven 16-series form, persistent
//   register fragments, XOR-swizzled slab, 2 barriers/step. EXACT lstm_h.
//  blocks [NB_B, ...): teacher path (r9 structure, 117 us): stage ALL weights
//   + bias/head vectors once (39.7 KB), ONE barrier, then 4 barrier-free
//   staging-free tiles; memory clobber per tile defeats LICM (r8: VGPR 188).
//   NEW (r12): X/y register double-buffer across the backedge — tile t+1's
//   HBM loads issue inside tile t's body (hidden under ~2000 cyc compute);
//   tile 0's loads issue before staging (hidden under stage+barrier). The
//   clobber forced these loads onto the MFMA critical path; 9 loop-carried
//   VGPRs is far below the r6 spill threshold.
//  LDS union = 39680 B -> 4 blocks/CU (16 waves/CU), VGPR ~64.
// ---------------------------------------------------------------------------
__global__ __launch_bounds__(256, 6) void fused(
    const float* __restrict__ X,
    const float* __restrict__ y,
    const float* __restrict__ Xf,
    const float* __restrict__ W_embed,
    const float* __restrict__ b_embed,
    const _Float16* __restrict__ W16f,
    const float* __restrict__ bsum,
    const float* __restrict__ wy1,
    const float* __restrict__ b1c,
    const float* __restrict__ W_mu,
    const float* __restrict__ b_mu,
    const float* __restrict__ W_sigma,
    const float* __restrict__ b_sigma,
    float* __restrict__ out)
{
    __shared__ union __align__(16) {
        struct {                                           // teacher: 39680 B
            _Float16 Wl0[6144]; _Float16 Wlh[2][6144];
            float b1cb[NROW]; float wy1b[NROW]; float bs1b[NROW];
            float wmb[HID]; float wsb[HID];
        } A;
        struct { _Float16 slab[16 * 64]; float partm[16][4]; float parts[16][4];
                 float wyb[NROW]; float b1cb[NROW]; } B;                 // ~4.1 KB
    } sh;

    const int tid = threadIdx.x;
    float* mu_out = out + (size_t)N_TS * HOR;
    float* sg_out = mu_out + (size_t)N_TS * T_ALL;

    if (blockIdx.x < NB_B) {
        // =================== autoregressive path (4 waves) ===================
        __builtin_amdgcn_s_setprio(1);           // beat co-resident teacher waves
        const int w    = tid >> 6;
        const int lane = tid & 63;
        const int quad = lane >> 4;
        const int ln   = lane & 15;
        const int n0   = blockIdx.x * 16;

        if (tid < NROW) {
            sh.B.wyb[tid]  = wy1[tid];
            sh.B.b1cb[tid] = b1c[tid];
        }

        // persistent register fragments (wave w owns row-tiles rt = j*4+w)
        half8 B1[3];        // W1 rows, k<32 (embed cols via rank-1 fold)
        half8 B2[3][2];     // W2 rows, full k (STANDARD layout)
        float bias2[3];
        #pragma unroll
        for (int j = 0; j < 3; ++j) {
            const int rt = j * 4 + w;
            B1[j] = *(const half8*)(W16f + ((size_t)quad * NROW + rt * 16 + ln) * 8);
            #pragma unroll
            for (int kt = 0; kt < 2; ++kt)
                B2[j][kt] = *(const half8*)(W16f + W16F_L1 + ((size_t)(kt * 4 + quad) * NROW + rt * 16 + ln) * 8);
            bias2[j] = bsum[NROW + rt * 16 + ln];
        }
        const float wmu = W_mu[w * 16 + ln], wsg = W_sigma[w * 16 + ln];
        const float bmu = b_mu[0], bsg = b_sigma[0];

        // bootstrap inputs: t = 167
        const float* xfp = Xf + (size_t)(n0 + ln) * HOR * F_INP + quad * 8;
        float4 xa, xb;
        {
            const float* xp = X + ((size_t)(n0 + ln) * SEQ + (SEQ - 1)) * F_INP + quad * 8;
            xa = *(const float4*)xp;
            xb = *(const float4*)(xp + 4);
        }
        float ycur = y[(size_t)(n0 + ln) * SEQ + (SEQ - 1)];
        __syncthreads();                         // wyb/b1cb visible

        #pragma unroll 1
        for (int it = 0; it <= HOR + 1; ++it) {
            if (it > 0) {
                // finalize step k = it-1 (redundant per-lane, bit-identical)
                const int k = it - 1;
                const float4 m4 = *(const float4*)sh.B.partm[ln];
                const float4 s4 = *(const float4*)sh.B.parts[ln];
                const float mu = (m4.x + m4.y) + (m4.z + m4.w) + bmu;
                const float sg = softplus_((s4.x + s4.y) + (s4.z + s4.w) + bsg) + 1e-6f;
                const float d  = ycur - mu;
                const float is = frcp(sg);
                const float lik = 0.39894228040143267f * is * fexp(-0.5f * d * d * is * is);
                if (k > 0 && w == 0 && quad == 0) {
                    const int nn = n0 + ln;
                    const int t  = SEQ + k - 1;
                    mu_out[(size_t)nn * T_ALL + t] = mu;
                    sg_out[(size_t)nn * T_ALL + t] = sg;
                    if (k < HOR) out[(size_t)nn * HOR + k] = lik;
                }
                ycur = lik;
            }
            if (it > HOR) break;

            // ---- compute step it (input carry = ycur) ----
            const half8 xf0 = cvt8(xa, xb);
            if (it < HOR) {                      // next iter uses Xf step it
                xa = *(const float4*)(xfp + it * F_INP);
                xb = *(const float4*)(xfp + it * F_INP + 4);
            }

            // layer 1: 3 MFMAs; C row = unit-in-tile (quad*4+r), col = series(ln)
            floatx4 t0 = *(const floatx4*)(sh.B.b1cb + 0 * 64 + w * 16 + quad * 4);
            floatx4 t1 = *(const floatx4*)(sh.B.b1cb + 1 * 64 + w * 16 + quad * 4);
            floatx4 t2 = *(const floatx4*)(sh.B.b1cb + 2 * 64 + w * 16 + quad * 4);
            t0 = __builtin_amdgcn_mfma_f32_16x16x32_f16(B1[0], xf0, t0, 0, 0, 0);
            t1 = __builtin_amdgcn_mfma_f32_16x16x32_f16(B1[1], xf0, t1, 0, 0, 0);
            t2 = __builtin_amdgcn_mfma_f32_16x16x32_f16(B1[2], xf0, t2, 0, 0, 0);

            const floatx4 wy0  = *(const floatx4*)(sh.B.wyb + 0 * 64 + w * 16 + quad * 4);
            const floatx4 wy1v = *(const floatx4*)(sh.B.wyb + 1 * 64 + w * 16 + quad * 4);
            const floatx4 wy2  = *(const floatx4*)(sh.B.wyb + 2 * 64 + w * 16 + quad * 4);

            half4 h1p;
            #pragma unroll
            for (int r = 0; r < 4; ++r) {
                const float ig = fmaf(ycur, wy0[r],  t0[r]);
                const float gg = fmaf(ycur, wy1v[r], t1[r]);
                const float og = fmaf(ycur, wy2[r],  t2[r]);
                h1p[r] = (_Float16)lstm_h(ig, gg, og);
            }
            // XOR-swizzled slab write: unit 16B-block = 2*w + (quad>>1)
            {
                const int xblk = (2 * w + (quad >> 1)) ^ (ln & 7);
                *(half4*)(&sh.B.slab[ln * 64 + xblk * 8 + (quad & 1) * 4]) = h1p;
            }
            __syncthreads();

            // layer 2: A = h1 series-frag (swizzled reads)
            const half8 a0 = *(const half8*)(&sh.B.slab[ln * 64 + ((quad ^ (ln & 7)) << 3)]);
            const half8 a1 = *(const half8*)(&sh.B.slab[ln * 64 + (((4 + quad) ^ (ln & 7)) << 3)]);
            floatx4 acc[3];
            #pragma unroll
            for (int j = 0; j < 3; ++j) {
                acc[j] = (floatx4){bias2[j], bias2[j], bias2[j], bias2[j]};
                acc[j] = __builtin_amdgcn_mfma_f32_16x16x32_f16(a0, B2[j][0], acc[j], 0, 0, 0);
                acc[j] = __builtin_amdgcn_mfma_f32_16x16x32_f16(a1, B2[j][1], acc[j], 0, 0, 0);
            }

            // act L2 + head partials: unit w*16+ln, series quad*4+r
            float pmr[4], psr[4];
            #pragma unroll
            for (int r = 0; r < 4; ++r) {
                const float hh = lstm_h(acc[0][r], acc[1][r], acc[2][r]);
                const float hr = fmaxf(hh, 0.0f);
                pmr[r] = hr * wmu;
                psr[r] = hr * wsg;
            }
            #pragma unroll
            for (int off = 1; off < 16; off <<= 1) {
                #pragma unroll
                for (int r = 0; r < 4; ++r) {
                    pmr[r] += __shfl_xor(pmr[r], off, 64);
                    psr[r] += __shfl_xor(psr[r], off, 64);
                }
            }
            if (ln == 0) {
                #pragma unroll
                for (int r = 0; r < 4; ++r) {
                    sh.B.partm[quad * 4 + r][w] = pmr[r];
                    sh.B.parts[quad * 4 + r][w] = psr[r];
                }
            }
            __syncthreads();
        }
        return;
    }

    // ======================= teacher-forced path (4 waves) =======================
    const int w    = tid >> 6;
    const int lane = tid & 63;
    const int quad = lane >> 4;
    const int ln   = lane & 15;
    const int tile0 = (blockIdx.x - NB_B) * 4;

    // prefetch tile 0 inputs — completes under the staging + barrier below
    float4 xa, xb;
    float yvn;
    {
        const int cid0 = tile0 * 64 + w * 16 + ln;
        const float* xp = X + (size_t)cid0 * F_INP + quad * 8;
        xa  = *(const float4*)xp;
        xb  = *(const float4*)(xp + 4);
        yvn = y[cid0];
    }

    // ---- one-time stage: L0 (12K) + both L1P halves (24K) + bias/head vecs ----
    #pragma unroll
    for (int c = 0; c < 3; ++c) {
        const int off = (c * 256 + tid) * 8;
        *(half8*)(sh.A.Wl0 + off)    = *(const half8*)(W16f + off);
        *(half8*)(sh.A.Wlh[0] + off) = *(const half8*)(W16f + W16F_L1P + off);
        *(half8*)(sh.A.Wlh[1] + off) = *(const half8*)(W16f + W16F_L1P + 6144 + off);
    }
    if (tid < NROW) {
        sh.A.b1cb[tid] = b1c[tid];
        sh.A.wy1b[tid] = wy1[tid];
        sh.A.bs1b[tid] = bsum[NROW + tid];
    }
    if (tid < HID) { sh.A.wmb[tid] = W_mu[tid]; sh.A.wsb[tid] = W_sigma[tid]; }
    __syncthreads();                 // the ONLY barrier in this path

    const _Float16* bp0 = sh.A.Wl0 + quad * 1536 + ln * 8;     // (kb=quad)*192 rows

    #pragma unroll 1
    for (int tt = 0; tt < 4; ++tt) {
        // defeat LICM: force all loop-invariant loads to stay inside the loop
        // (r8 lesson: hoisting them ballooned VGPR 40->188, occupancy 61->11%)
        asm volatile("" ::: "memory");

        const int cid = (tile0 + tt) * 64 + w * 16 + ln;

        // consume prefetched inputs; issue next tile's loads (hidden under body)
        const half8 xfr = cvt8(xa, xb);
        const float yv  = yvn;
        if (tt < 3) {
            const float* xp = X + (size_t)(cid + 64) * F_INP + quad * 8;
            xa  = *(const float4*)xp;
            xb  = *(const float4*)(xp + 4);
            yvn = y[cid + 64];
        }

        // L0: outputs written STRAIGHT into the L1 B-fragments (pi-permuted
        // weights make the lane's own 16 h1 values its fragment; no exchange).
        half8 a0, a1;
        #pragma unroll
        for (int jt = 0; jt < 4; ++jt) {
            // bias init from resident LDS (f32, prescaled, embed-bias folded)
            floatx4 ai = *(const floatx4*)(sh.A.b1cb + jt * 16 + quad * 4);
            floatx4 ag = *(const floatx4*)(sh.A.b1cb + 64 + jt * 16 + quad * 4);
            floatx4 ao = *(const floatx4*)(sh.A.b1cb + 128 + jt * 16 + quad * 4);
            ai = __builtin_amdgcn_mfma_f32_16x16x32_f16(*(const half8*)(bp0 + jt * 128),        xfr, ai, 0, 0, 0);
            ag = __builtin_amdgcn_mfma_f32_16x16x32_f16(*(const half8*)(bp0 + 512 + jt * 128),  xfr, ag, 0, 0, 0);
            ao = __builtin_amdgcn_mfma_f32_16x16x32_f16(*(const half8*)(bp0 + 1024 + jt * 128), xfr, ao, 0, 0, 0);
            // rank-1 y fold (f32)
            const floatx4 wyi = *(const floatx4*)(sh.A.wy1b + jt * 16 + quad * 4);
            const floatx4 wyg = *(const floatx4*)(sh.A.wy1b + 64 + jt * 16 + quad * 4);
            const floatx4 wyo = *(const floatx4*)(sh.A.wy1b + 128 + jt * 16 + quad * 4);
            a0[2 * jt + 0] = (_Float16)lstm_h_fast(fmaf(yv, wyi[0], ai[0]),
                                                   fmaf(yv, wyg[0], ag[0]),
                                                   fmaf(yv, wyo[0], ao[0]));
            a0[2 * jt + 1] = (_Float16)lstm_h_fast(fmaf(yv, wyi[1], ai[1]),
                                                   fmaf(yv, wyg[1], ag[1]),
                                                   fmaf(yv, wyo[1], ao[1]));
            a1[2 * jt + 0] = (_Float16)lstm_h_fast(fmaf(yv, wyi[2], ai[2]),
                                                   fmaf(yv, wyg[2], ag[2]),
                                                   fmaf(yv, wyo[2], ao[2]));
            a1[2 * jt + 1] = (_Float16)lstm_h_fast(fmaf(yv, wyi[3], ai[3]),
                                                   fmaf(yv, wyg[3], ag[3]),
                                                   fmaf(yv, wyo[3], ao[3]));
        }

        // ---- L1 in two phases from resident LDS (no staging, no barriers) ----
        float pm = 0.f, ps = 0.f;
        #pragma unroll
        for (int h = 0; h < 2; ++h) {
            const _Float16* bp = sh.A.Wlh[h] + quad * 768 + ln * 8;  // kb=quad (96 rows)
            #pragma unroll
            for (int jtl = 0; jtl < 2; ++jtl) {
                const int jt = h * 2 + jtl;
                floatx4 ai = *(const floatx4*)(sh.A.bs1b + jt * 16 + quad * 4);
                floatx4 ag = *(const floatx4*)(sh.A.bs1b + 64 + jt * 16 + quad * 4);
                floatx4 ao = *(const floatx4*)(sh.A.bs1b + 128 + jt * 16 + quad * 4);
                ai = __builtin_amdgcn_mfma_f32_16x16x32_f16(*(const half8*)(bp + jtl * 128),               a0, ai, 0, 0, 0);
                ai = __builtin_amdgcn_mfma_f32_16x16x32_f16(*(const half8*)(bp + jtl * 128 + 3072),        a1, ai, 0, 0, 0);
                ag = __builtin_amdgcn_mfma_f32_16x16x32_f16(*(const half8*)(bp + 256 + jtl * 128),         a0, ag, 0, 0, 0);
                ag = __builtin_amdgcn_mfma_f32_16x16x32_f16(*(const half8*)(bp + 256 + jtl * 128 + 3072),  a1, ag, 0, 0, 0);
                ao = __builtin_amdgcn_mfma_f32_16x16x32_f16(*(const half8*)(bp + 512 + jtl * 128),         a0, ao, 0, 0, 0);
                ao = __builtin_amdgcn_mfma_f32_16x16x32_f16(*(const half8*)(bp + 512 + jtl * 128 + 3072),  a1, ao, 0, 0, 0);
                // head partials in-thread: rows hid = jt*16+quad*4+r, inst = ln
                const floatx4 wm  = *(const floatx4*)(sh.A.wmb + jt * 16 + quad * 4);
                const floatx4 ws4 = *(const floatx4*)(sh.A.wsb + jt * 16 + quad * 4);
                #pragma unroll
                for (int r = 0; r < 4; ++r) {
                    const float hr = fmaxf(lstm_h_fast(ai[r], ag[r], ao[r]), 0.0f);
                    pm = fmaf(hr, wm[r], pm);
                    ps = fmaf(hr, ws4[r], ps);
                }
            }
        }

        // reduce over quads only (hid split across quads; inst=ln is lane-local)
        pm += __shfl_xor(pm, 16, 64); pm += __shfl_xor(pm, 32, 64);
        ps += __shfl_xor(ps, 16, 64); ps += __shfl_xor(ps, 32, 64);

        if (quad == 0) {
            const int n = cid / SEQ;
            const int t = cid - n * SEQ;
            const float mu = pm + b_mu[0];
            const float sg = softplus_(ps + b_sigma[0]) + 1e-6f;
            mu_out[(size_t)n * T_ALL + t] = mu;
            sg_out[(size_t)n * T_ALL + t] = sg;
            if (t == SEQ - 1) {
                const float d  = yv - mu;
                const float is = frcp(sg);
                out[(size_t)n * HOR] = 0.39894228040143267f * is * fexp(-0.5f * d * d * is * is);
            }
        }
    }
}

extern "C" void kernel_launch(void* const* d_in, const int* in_sizes, int n_in,
                              void* d_out, int out_size, void* d_ws, size_t ws_size,
                              hipStream_t stream) {
    const float* X       = (const float*)d_in[0];
    const float* y       = (const float*)d_in[1];
    const float* Xf      = (const float*)d_in[2];
    const float* W_embed = (const float*)d_in[3];
    const float* b_embed = (const float*)d_in[4];
    const float* W_ih    = (const float*)d_in[5];
    const float* b_ih    = (const float*)d_in[6];
    const float* b_hh    = (const float*)d_in[7];
    const float* W_mu    = (const float*)d_in[8];
    const float* b_mu    = (const float*)d_in[9];
    const float* W_sigma = (const float*)d_in[10];
    const float* b_sigma = (const float*)d_in[11];

    float* out = (float*)d_out;
    // ws: W16f(61440 B: L0 12KB + L1std 24KB + L1perm 24KB) | bsum(1536) | wy1(768) | b1c(768)
    _Float16*  W16f = (_Float16*)d_ws;
    float*     bsum = (float*)((char*)d_ws + 61440);
    float*     wy1  = (float*)((char*)d_ws + 61440 + 1536);
    float*     b1c  = (float*)((char*)d_ws + 61440 + 1536 + 768);

    prep<<<96, 256, 0, stream>>>(W_ih, b_ih, b_hh, W_embed, b_embed,
                                 W16f, bsum, wy1, b1c);

    fused<<<NB_B + NT_B, 256, 0, stream>>>(
        X, y, Xf, W_embed, b_embed, W16f, bsum, wy1, b1c,
        W_mu, b_mu, W_sigma, b_sigma, out);
}